// Round 9
// baseline (293.804 us; speedup 1.0000x reference)
//
#include <hip/hip_runtime.h>
#include <cstdint>
#include <cstddef>

#define SEQ 2048
#define DIM 512

using floatx4 = __attribute__((ext_vector_type(4))) float;
using halfx8  = __attribute__((ext_vector_type(8))) _Float16;

__device__ __forceinline__ ushort f2h(float f) {
    _Float16 h = (_Float16)f;
    return __builtin_bit_cast(unsigned short, h);
}

// ---------------- prep: x->fp16, W->fp16 cat, bias cat, rowsum zero ----------------
__global__ void prep_k(const float* __restrict__ x,
                       const float* __restrict__ Wq, const float* __restrict__ Wk,
                       const float* __restrict__ Wv,
                       const float* __restrict__ bq, const float* __restrict__ bk,
                       const float* __restrict__ bv,
                       ushort* __restrict__ xh, ushort* __restrict__ wcat,
                       float* __restrict__ bcat, float* __restrict__ rowsum) {
    int i = blockIdx.x * 256 + threadIdx.x;
    if (i < 1048576) {
        float4 v = ((const float4*)x)[i];
        ((ushort4*)xh)[i] = make_ushort4(f2h(v.x), f2h(v.y), f2h(v.z), f2h(v.w));
    } else if (i < 1048576 + 196608) {
        int j = i - 1048576;
        int which = j >> 16;
        const float* w = (which == 0) ? Wq : (which == 1) ? Wk : Wv;
        float4 v = ((const float4*)w)[j & 0xFFFF];
        ((ushort4*)wcat)[j] = make_ushort4(f2h(v.x), f2h(v.y), f2h(v.z), f2h(v.w));
    } else if (i < 1048576 + 196608 + 384) {
        int j = i - 1245184;
        const float* bsrc = (j < 128) ? bq : (j < 256) ? bk : bv;
        ((float4*)bcat)[j] = ((const float4*)bsrc)[j & 127];
    } else if (i < 1048576 + 196608 + 384 + 2048) {
        int j = i - 1245568;
        ((float4*)rowsum)[j] = (float4){0.f, 0.f, 0.f, 0.f};
    }
}

// ------- barrier-free wave-block NT GEMM: 1 wave, 64x64 tile, regs-direct ----------
// Operand fragments loaded straight global->VGPR (16B/lane, 64B-coalesced segments).
// No LDS staging, no __syncthreads in the K-loop; reg-double-buffered, unroll x2.
// EPI 0 = QKV: n0<1024 -> q/k via Ps (+bias); n0>=1024 -> v transposed to vt.
// EPI 1 = SCORES: P = exp(acc*alpha) fp16 via Ps; rowsum 1 atomic per lane-row.
// EPI 2 = PV split-K=4: normalized fp16 partial via Ps (acc * rcp(rowsum)).

template<int EPI>
__global__ __launch_bounds__(64, 3)
void gemm_w(const ushort* __restrict__ A, const ushort* __restrict__ B,
            void* __restrict__ Cout, const float* __restrict__ bias,
            float* __restrict__ rowsum, ushort* __restrict__ vt,
            int lda, int ldb, int ldc, int kIters, float alpha,
            long sA, long sB, long sC)
{
    __shared__ ushort Ps[64 * 66];   // stride 66: dword-aligned rows, conflict-free

    const int tid = threadIdx.x;     // 0..63, one wave
    const int bz = blockIdx.z;
    int b, kofs;
    if (EPI == 2) { b = bz & 3; kofs = (bz >> 2) * 512; }
    else          { b = bz; kofs = 0; }
    const ushort* Ab = A + (size_t)b * sA + kofs;
    const ushort* Bb = B + (size_t)b * sB + kofs;

    const int m0 = blockIdx.y * 64;
    const int n0 = blockIdx.x * 64;
    const int quad = tid >> 4, l16 = tid & 15;

    const ushort* aP[4];
    const ushort* bP[4];
#pragma unroll
    for (int i = 0; i < 4; i++) {
        aP[i] = Ab + (size_t)(m0 + i * 16 + l16) * lda + quad * 8;
        bP[i] = Bb + (size_t)(n0 + i * 16 + l16) * ldb + quad * 8;
    }

    floatx4 acc[4][4];
#pragma unroll
    for (int i = 0; i < 4; i++)
#pragma unroll
        for (int j = 0; j < 4; j++)
            acc[i][j] = (floatx4){0.f, 0.f, 0.f, 0.f};

    halfx8 a0[4], b0[4], a1[4], b1[4];
#pragma unroll
    for (int i = 0; i < 4; i++) {
        a0[i] = *(const halfx8*)(aP[i]);
        b0[i] = *(const halfx8*)(bP[i]);
    }

    for (int it = 0; it < kIters; it += 2) {
        const int k1 = (it + 1) * 32;
#pragma unroll
        for (int i = 0; i < 4; i++) {
            a1[i] = *(const halfx8*)(aP[i] + k1);
            b1[i] = *(const halfx8*)(bP[i] + k1);
        }
#pragma unroll
        for (int mi = 0; mi < 4; mi++)
#pragma unroll
            for (int ni = 0; ni < 4; ni++)
                acc[mi][ni] = __builtin_amdgcn_mfma_f32_16x16x32_f16(a0[mi], b0[ni], acc[mi][ni], 0, 0, 0);
        if (it + 2 < kIters) {
            const int k2 = (it + 2) * 32;
#pragma unroll
            for (int i = 0; i < 4; i++) {
                a0[i] = *(const halfx8*)(aP[i] + k2);
                b0[i] = *(const halfx8*)(bP[i] + k2);
            }
        }
#pragma unroll
        for (int mi = 0; mi < 4; mi++)
#pragma unroll
            for (int ni = 0; ni < 4; ni++)
                acc[mi][ni] = __builtin_amdgcn_mfma_f32_16x16x32_f16(a1[mi], b1[ni], acc[mi][ni], 0, 0, 0);
    }

    if (EPI == 0 && n0 >= 1024) {
        // v path: transpose into vt[b*512+e][j], 4 consecutive rows(j) pack to 8B
#pragma unroll
        for (int ni = 0; ni < 4; ni++) {
            int col = n0 + ni * 16 + l16;
            float bv = bias[col];
            int e = col - 1024;
#pragma unroll
            for (int mi = 0; mi < 4; mi++) {
                int row0 = m0 + mi * 16 + quad * 4;
                int bb = row0 >> 11;
                int j = row0 & 2047;
                ushort4 pk = make_ushort4(f2h(acc[mi][ni][0] + bv), f2h(acc[mi][ni][1] + bv),
                                          f2h(acc[mi][ni][2] + bv), f2h(acc[mi][ni][3] + bv));
                *(ushort4*)&vt[((size_t)(bb << 9) + e) * 2048 + j] = pk;
            }
        }
    } else {
        // write phase: C-fragment -> Ps (stride 66)
        float bvv[4];
        if (EPI == 0) {
#pragma unroll
            for (int ni = 0; ni < 4; ni++) bvv[ni] = bias[n0 + ni * 16 + l16];
        }
        float inv[4][4];
        if (EPI == 2) {
#pragma unroll
            for (int mi = 0; mi < 4; mi++)
#pragma unroll
                for (int r = 0; r < 4; r++)
                    inv[mi][r] = __builtin_amdgcn_rcpf(
                        rowsum[b * SEQ + m0 + mi * 16 + quad * 4 + r]);
        }
#pragma unroll
        for (int mi = 0; mi < 4; mi++)
#pragma unroll
            for (int ni = 0; ni < 4; ni++) {
                int col_l = ni * 16 + l16;
#pragma unroll
                for (int r = 0; r < 4; r++) {
                    int row_l = mi * 16 + quad * 4 + r;
                    float v = (EPI == 1) ? __expf(acc[mi][ni][r] * alpha)
                            : (EPI == 2) ? acc[mi][ni][r] * inv[mi][r]
                                         : acc[mi][ni][r] + bvv[ni];
                    Ps[row_l * 66 + col_l] = f2h(v);
                }
            }
        // readback: lane = row (same wave; lgkmcnt ordering is automatic, no barrier)
        int rr = tid;
        size_t base = (EPI == 1) ? (size_t)b * sC : (EPI == 2) ? (size_t)bz * sC : 0;
        ushort* dstrow = (ushort*)Cout + base + (size_t)(m0 + rr) * ldc + n0;
        float s = 0.f;
#pragma unroll
        for (int c = 0; c < 8; c++) {
            union { uint32_t u[4]; halfx8 h; } U;
#pragma unroll
            for (int q = 0; q < 4; q++)
                U.u[q] = *(const uint32_t*)&Ps[rr * 66 + c * 8 + q * 2];
            if (EPI == 1) {
#pragma unroll
                for (int e = 0; e < 8; e++) s += (float)U.h[e];
            }
            *(halfx8*)(dstrow + c * 8) = U.h;
        }
        if (EPI == 1) atomicAdd(&rowsum[b * SEQ + m0 + rr], s);
    }
}

// ---------------- sum 4 normalized fp16 split-K partials -> fp32 out ----------------
__global__ void reduce_k(const ushort* __restrict__ part, float* __restrict__ out) {
    int t = blockIdx.x * 256 + threadIdx.x;
    size_t E = (size_t)t * 8;
    int b = (int)(E >> 20);
    size_t le = E & ((1u << 20) - 1);
    float acc[8] = {0,0,0,0,0,0,0,0};
#pragma unroll
    for (int kc = 0; kc < 4; kc++) {
        halfx8 p = *(const halfx8*)&part[(((size_t)(kc * 4 + b)) << 20) + le];
#pragma unroll
        for (int e = 0; e < 8; e++) acc[e] += (float)p[e];
    }
    float4 o0 = {acc[0], acc[1], acc[2], acc[3]};
    float4 o1 = {acc[4], acc[5], acc[6], acc[7]};
    ((float4*)(out + E))[0] = o0;
    ((float4*)(out + E))[1] = o1;
}

// ---------------- launch ----------------
extern "C" void kernel_launch(void* const* d_in, const int* in_sizes, int n_in,
                              void* d_out, int out_size, void* d_ws, size_t ws_size,
                              hipStream_t stream) {
    const float* x  = (const float*)d_in[0];
    const float* Wq = (const float*)d_in[1];
    const float* bq = (const float*)d_in[2];
    const float* Wk = (const float*)d_in[3];
    const float* bk = (const float*)d_in[4];
    const float* Wv = (const float*)d_in[5];
    const float* bv = (const float*)d_in[6];
    float* out = (float*)d_out;
    char* ws = (char*)d_ws;

    // ws layout. partial (fp16, written by PV) overlays xh/wcat/bcat (dead after QKV).
    ushort* partial = (ushort*)(ws);                // 33,554,432 (16 slabs fp16 [2048][512])
    ushort* xh      = (ushort*)(ws);                //  8,388,608 (alias, early phase)
    ushort* wcat    = (ushort*)(ws + 8388608);      //  1,572,864 (alias, early phase)
    float*  bcat    = (float*)(ws + 9961472);       //      6,144 (alias, early phase)
    float*  rowsum  = (float*)(ws + 33554432);      //     32,768
    ushort* Pb      = (ushort*)(ws + 33587200);     // 33,554,432 fp16 exp(s)
    ushort* vt      = (ushort*)(ws + 67141632);     //  8,388,608 fp16 v transposed
    ushort* qkh     = (ushort*)(ws + 75530240);     // 33,554,432 fp16 q|k, ld 1024
    // total 109,084,672

    prep_k<<<4874, 256, 0, stream>>>(x, Wq, Wk, Wv, bq, bk, bv, xh, wcat, bcat, rowsum);

    // QKV: q/k -> qkh [8192,1024]; v -> vt [4*512,2048] transposed. K=512.
    gemm_w<0><<<dim3(24, 128, 1), 64, 0, stream>>>(
        xh, wcat, qkh, bcat, nullptr, vt, 512, 512, 1024, 16, 1.0f, 0, 0, 0);

    // scores: P = exp(scale * q@k^T) fp16 [b][2048][2048], rowsum fp32
    const float scale = 0.04419417382415922f;  // 1/sqrt(512)
    gemm_w<1><<<dim3(32, 32, 4), 64, 0, stream>>>(
        qkh, qkh + 512, Pb, nullptr, rowsum, nullptr, 1024, 1024, 2048, 16, scale,
        (long)SEQ * 1024, (long)SEQ * 1024, (long)SEQ * SEQ);

    // PV split-K=4: partial[kc*4+b][2048][512] = (P[:,kc*512:+512] @ vt^T) / rowsum
    gemm_w<2><<<dim3(8, 32, 16), 64, 0, stream>>>(
        Pb, vt, partial, nullptr, rowsum, nullptr, 2048, 2048, 512, 16, 1.0f,
        (long)SEQ * SEQ, (long)DIM * SEQ, (long)SEQ * DIM);

    reduce_k<<<2048, 256, 0, stream>>>(partial, out);
}

// Round 10
// 167.354 us; speedup vs baseline: 1.7556x; 1.7556x over previous
//
#include <hip/hip_runtime.h>
#include <cstdint>
#include <cstddef>

#define SEQ 2048
#define DIM 512

using floatx4 = __attribute__((ext_vector_type(4))) float;
using halfx8  = __attribute__((ext_vector_type(8))) _Float16;

__device__ __forceinline__ ushort f2h(float f) {
    _Float16 h = (_Float16)f;
    return __builtin_bit_cast(unsigned short, h);
}

#define GLL(g, l) __builtin_amdgcn_global_load_lds( \
    (const __attribute__((address_space(1))) uint32_t*)(g), \
    (__attribute__((address_space(3))) uint32_t*)(l), 16, 0, 0)

// ---------------- prep: x->fp16, W->fp16 cat, bias cat, rowsum zero ----------------
__global__ void prep_k(const float* __restrict__ x,
                       const float* __restrict__ Wq, const float* __restrict__ Wk,
                       const float* __restrict__ Wv,
                       const float* __restrict__ bq, const float* __restrict__ bk,
                       const float* __restrict__ bv,
                       ushort* __restrict__ xh, ushort* __restrict__ wcat,
                       float* __restrict__ bcat, float* __restrict__ rowsum) {
    int i = blockIdx.x * 256 + threadIdx.x;
    if (i < 1048576) {
        float4 v = ((const float4*)x)[i];
        ((ushort4*)xh)[i] = make_ushort4(f2h(v.x), f2h(v.y), f2h(v.z), f2h(v.w));
    } else if (i < 1048576 + 196608) {
        int j = i - 1048576;
        int which = j >> 16;
        const float* w = (which == 0) ? Wq : (which == 1) ? Wk : Wv;
        float4 v = ((const float4*)w)[j & 0xFFFF];
        ((ushort4*)wcat)[j] = make_ushort4(f2h(v.x), f2h(v.y), f2h(v.z), f2h(v.w));
    } else if (i < 1048576 + 196608 + 384) {
        int j = i - 1245184;
        const float* bsrc = (j < 128) ? bq : (j < 256) ? bk : bv;
        ((float4*)bcat)[j] = ((const float4*)bsrc)[j & 127];
    } else if (i < 1048576 + 196608 + 384 + 2048) {
        int j = i - 1245568;
        ((float4*)rowsum)[j] = (float4){0.f, 0.f, 0.f, 0.f};
    }
}

// ---- NT GEMM, TMx128xBK32 tile, TM*2 threads, double-buffered LDS staging ---------
// TM=128: 4 waves 2x2 (round-5 verified epilogue); TM=256: 8 waves 4x2 (round-8).
// EPI 0 = QKV: n0<1024 -> q/k via Ps (+bias); n0>=1024 -> v transposed to vt.
// EPI 1 = SCORES: P = exp(acc*alpha) fp16 via Ps; fp32 rowsum atomics.
// EPI 2 = PV split-K=2 (kofs=(bz>>2)*1024): normalized fp16 partial via Ps.

template<int EPI, int TM>
__global__ __launch_bounds__(TM * 2, 4)
void gemm_k(const ushort* __restrict__ A, const ushort* __restrict__ B,
            void* __restrict__ Cout, const float* __restrict__ bias,
            float* __restrict__ rowsum, ushort* __restrict__ vt,
            int lda, int ldb, int ldc, int kIters, float alpha,
            long sA, long sB, long sC)
{
    constexpr int T = TM * 2;
    // layout: A buf0 [0,TM*32) | A buf1 | B buf0 (4096) | B buf1 ; Ps aliases first 32KB
    __shared__ __align__(16) ushort smem[TM * 64 + 128 * 64];
    ushort* Ps = smem;

    const int tid = threadIdx.x;
    const int bz = blockIdx.z;
    int b, kofs;
    if (EPI == 2) { b = bz & 3; kofs = (bz >> 2) * 1024; }
    else          { b = bz; kofs = 0; }
    const ushort* Ab = A + (size_t)b * sA + kofs;
    const ushort* Bb = B + (size_t)b * sB + kofs;

    const int m0 = blockIdx.y * TM;
    const int n0 = blockIdx.x * 128;
    const int lane = tid & 63, wave = tid >> 6;
    const int wm = (wave >> 1) * 64, wn = (wave & 1) * 64;
    const int quad = lane >> 4, l16 = lane & 15;
    const int swz = (l16 >> 1) & 3;

    // staging slots (slot s: row s>>2, k-chunk (s&3)^((row>>1)&3))
    const int sA0 = tid, sA1 = tid + T;
    const int rA0 = sA0 >> 2, rA1 = sA1 >> 2;
    const int kA0 = (sA0 & 3) ^ ((rA0 >> 1) & 3);
    const int kA1 = (sA1 & 3) ^ ((rA1 >> 1) & 3);
    const ushort* gA0 = Ab + (size_t)(m0 + rA0) * lda + kA0 * 8;
    const ushort* gA1 = Ab + (size_t)(m0 + rA1) * lda + kA1 * 8;
    const int rB0 = tid >> 2;
    const int kB0 = (tid & 3) ^ ((rB0 >> 1) & 3);
    const ushort* gB0 = Bb + (size_t)(n0 + rB0) * ldb + kB0 * 8;
    const ushort* gB1 = nullptr;
    int sB1 = 0;
    if constexpr (TM == 128) {
        sB1 = tid + 256;
        int rB1 = sB1 >> 2;
        int kB1 = (sB1 & 3) ^ ((rB1 >> 1) & 3);
        gB1 = Bb + (size_t)(n0 + rB1) * ldb + kB1 * 8;
    }

    auto STAGE = [&](int kk, int bufi) {
        int ko = kk * 32;
        ushort* Ad = smem + bufi * (TM * 32);
        ushort* Bd = smem + TM * 64 + bufi * 4096;
        GLL(gA0 + ko, Ad + sA0 * 8);
        GLL(gA1 + ko, Ad + sA1 * 8);
        GLL(gB0 + ko, Bd + tid * 8);
        if constexpr (TM == 128) GLL(gB1 + ko, Bd + sB1 * 8);
    };

    int ofsA[4], ofsB[4];
#pragma unroll
    for (int mi = 0; mi < 4; mi++)
        ofsA[mi] = ((wm + mi * 16 + l16) * 4 + (quad ^ swz)) * 8;
#pragma unroll
    for (int ni = 0; ni < 4; ni++)
        ofsB[ni] = ((wn + ni * 16 + l16) * 4 + (quad ^ swz)) * 8;

    floatx4 acc[4][4];
#pragma unroll
    for (int i = 0; i < 4; i++)
#pragma unroll
        for (int j = 0; j < 4; j++)
            acc[i][j] = (floatx4){0.f, 0.f, 0.f, 0.f};

    STAGE(0, 0);
    for (int it = 0; it < kIters; ++it) {
        __syncthreads();
        const int buf = it & 1;
        if (it + 1 < kIters) STAGE(it + 1, buf ^ 1);
        const ushort* Ad = smem + buf * (TM * 32);
        const ushort* Bd = smem + TM * 64 + buf * 4096;
        halfx8 af[4], bfr[4];
#pragma unroll
        for (int mi = 0; mi < 4; mi++) af[mi] = *(const halfx8*)&Ad[ofsA[mi]];
#pragma unroll
        for (int ni = 0; ni < 4; ni++) bfr[ni] = *(const halfx8*)&Bd[ofsB[ni]];
#pragma unroll
        for (int mi = 0; mi < 4; mi++)
#pragma unroll
            for (int ni = 0; ni < 4; ni++)
                acc[mi][ni] = __builtin_amdgcn_mfma_f32_16x16x32_f16(af[mi], bfr[ni], acc[mi][ni], 0, 0, 0);
    }

    if (EPI == 0 && n0 >= 1024) {
        // v path: transpose into vt[b*512+e][j], 4 consecutive rows(j) pack to 8B
#pragma unroll
        for (int ni = 0; ni < 4; ni++) {
            int col = n0 + wn + ni * 16 + l16;
            float bv = bias[col];
            int e = col - 1024;
#pragma unroll
            for (int mi = 0; mi < 4; mi++) {
                int row0 = m0 + wm + mi * 16 + quad * 4;
                int bb = row0 >> 11;
                int j = row0 & 2047;
                ushort4 pk = make_ushort4(f2h(acc[mi][ni][0] + bv), f2h(acc[mi][ni][1] + bv),
                                          f2h(acc[mi][ni][2] + bv), f2h(acc[mi][ni][3] + bv));
                *(ushort4*)&vt[((size_t)(bb << 9) + e) * 2048 + j] = pk;
            }
        }
    } else {
        float bvv[4];
        if (EPI == 0) {
#pragma unroll
            for (int ni = 0; ni < 4; ni++) bvv[ni] = bias[n0 + wn + ni * 16 + l16];
        }
        float inv[4][4];
        if (EPI == 2) {
#pragma unroll
            for (int mi = 0; mi < 4; mi++)
#pragma unroll
                for (int r = 0; r < 4; r++)
                    inv[mi][r] = __builtin_amdgcn_rcpf(
                        rowsum[b * SEQ + m0 + wm + mi * 16 + quad * 4 + r]);
        }
        size_t base = (EPI == 1) ? (size_t)b * sC : (EPI == 2) ? (size_t)bz * sC : 0;
        constexpr int NPASS = TM / 128;
        __syncthreads();   // all staging reads retired before Ps overwrite
#pragma unroll
        for (int p = 0; p < NPASS; ++p) {
            if (NPASS == 1 || (wm >> 7) == p) {
                int wml = wm & 127;
#pragma unroll
                for (int mi = 0; mi < 4; mi++)
#pragma unroll
                    for (int ni = 0; ni < 4; ni++) {
                        int col_l = wn + ni * 16 + l16;
                        int c = col_l >> 3, w = col_l & 7;
#pragma unroll
                        for (int r = 0; r < 4; r++) {
                            int row_l = wml + mi * 16 + quad * 4 + r;
                            float v = (EPI == 1) ? __expf(acc[mi][ni][r] * alpha)
                                    : (EPI == 2) ? acc[mi][ni][r] * inv[mi][r]
                                                 : acc[mi][ni][r] + bvv[ni];
                            Ps[row_l * 128 + ((c ^ (row_l & 7)) << 3) + w] = f2h(v);
                        }
                    }
            }
            __syncthreads();
            if constexpr (TM == 128) {
                int rr = tid >> 1, h = tid & 1;
                float s = 0.f;
                ushort* dstrow = (ushort*)Cout + base + (size_t)(m0 + rr) * ldc + n0;
#pragma unroll
                for (int j = 0; j < 8; j++) {
                    int c = h * 8 + j;
                    halfx8 pv = *(const halfx8*)&Ps[rr * 128 + ((c ^ (rr & 7)) << 3)];
                    if (EPI == 1) {
#pragma unroll
                        for (int e = 0; e < 8; e++) s += (float)pv[e];
                    }
                    *(halfx8*)(dstrow + c * 8) = pv;
                }
                if (EPI == 1) atomicAdd(&rowsum[b * SEQ + m0 + rr], s);
            } else {
                int rr = tid >> 2, t3 = tid & 3;
                float s = 0.f;
                ushort* dstrow = (ushort*)Cout + base + (size_t)(m0 + p * 128 + rr) * ldc + n0;
#pragma unroll
                for (int j = 0; j < 4; j++) {
                    int c = j * 4 + t3;
                    halfx8 pv = *(const halfx8*)&Ps[rr * 128 + ((c ^ (rr & 7)) << 3)];
                    if (EPI == 1) {
#pragma unroll
                        for (int e = 0; e < 8; e++) s += (float)pv[e];
                    }
                    *(halfx8*)(dstrow + c * 8) = pv;
                }
                if (EPI == 1) {
                    s += __shfl_xor(s, 1);
                    s += __shfl_xor(s, 2);
                    if (t3 == 0) atomicAdd(&rowsum[b * SEQ + m0 + p * 128 + rr], s);
                }
            }
            if (p + 1 < NPASS) __syncthreads();
        }
    }
}

// ---------------- sum 2 normalized fp16 split-K partials -> fp32 out ----------------
__global__ void reduce_k(const ushort* __restrict__ part, float* __restrict__ out) {
    int t = blockIdx.x * 256 + threadIdx.x;
    size_t E = (size_t)t * 8;
    int b = (int)(E >> 20);
    size_t le = E & ((1u << 20) - 1);
    float acc[8] = {0,0,0,0,0,0,0,0};
#pragma unroll
    for (int kc = 0; kc < 2; kc++) {
        halfx8 p = *(const halfx8*)&part[(((size_t)(kc * 4 + b)) << 20) + le];
#pragma unroll
        for (int e = 0; e < 8; e++) acc[e] += (float)p[e];
    }
    float4 o0 = {acc[0], acc[1], acc[2], acc[3]};
    float4 o1 = {acc[4], acc[5], acc[6], acc[7]};
    ((float4*)(out + E))[0] = o0;
    ((float4*)(out + E))[1] = o1;
}

// ---------------- launch ----------------
extern "C" void kernel_launch(void* const* d_in, const int* in_sizes, int n_in,
                              void* d_out, int out_size, void* d_ws, size_t ws_size,
                              hipStream_t stream) {
    const float* x  = (const float*)d_in[0];
    const float* Wq = (const float*)d_in[1];
    const float* bq = (const float*)d_in[2];
    const float* Wk = (const float*)d_in[3];
    const float* bk = (const float*)d_in[4];
    const float* Wv = (const float*)d_in[5];
    const float* bv = (const float*)d_in[6];
    float* out = (float*)d_out;
    char* ws = (char*)d_ws;

    // ws layout. partial (fp16, 8 slabs) overlays xh/wcat/bcat (dead after QKV).
    ushort* partial = (ushort*)(ws);                // 16,777,216 (8 slabs fp16 [2048][512])
    ushort* xh      = (ushort*)(ws);                //  8,388,608 (alias, early phase)
    ushort* wcat    = (ushort*)(ws + 8388608);      //  1,572,864 (alias, early phase)
    float*  bcat    = (float*)(ws + 9961472);       //      6,144 (alias, early phase)
    float*  rowsum  = (float*)(ws + 33554432);      //     32,768
    ushort* Pb      = (ushort*)(ws + 33587200);     // 33,554,432 fp16 exp(s)
    ushort* vt      = (ushort*)(ws + 67141632);     //  8,388,608 fp16 v transposed
    ushort* qkh     = (ushort*)(ws + 75530240);     // 33,554,432 fp16 q|k, ld 1024
    // total 109,084,672

    prep_k<<<4874, 256, 0, stream>>>(x, Wq, Wk, Wv, bq, bk, bv, xh, wcat, bcat, rowsum);

    // QKV: q/k -> qkh [8192,1024]; v -> vt [4*512,2048] transposed. K=512. 768 blocks.
    gemm_k<0, 128><<<dim3(12, 64, 1), 256, 0, stream>>>(
        xh, wcat, qkh, bcat, nullptr, vt, 512, 512, 1024, 16, 1.0f, 0, 0, 0);

    // scores: P = exp(scale * q@k^T) fp16 [b][2048][2048], rowsum fp32. 512 blocks.
    const float scale = 0.04419417382415922f;  // 1/sqrt(512)
    gemm_k<1, 256><<<dim3(16, 8, 4), 512, 0, stream>>>(
        qkh, qkh + 512, Pb, nullptr, rowsum, nullptr, 1024, 1024, 2048, 16, scale,
        (long)SEQ * 1024, (long)SEQ * 1024, (long)SEQ * SEQ);

    // PV split-K=2: partial[kc*4+b][2048][512] = (P[:,kc*1024:+1024] @ vt^T)/rowsum. 512 blocks, 32 iters.
    gemm_k<2, 128><<<dim3(4, 16, 8), 256, 0, stream>>>(
        Pb, vt, partial, nullptr, rowsum, nullptr, 2048, 2048, 512, 32, 1.0f,
        (long)SEQ * SEQ, (long)DIM * SEQ, (long)SEQ * DIM);

    reduce_k<<<2048, 256, 0, stream>>>(partial, out);
}